// Round 7
// baseline (1128.050 us; speedup 1.0000x reference)
//
#include <hip/hip_runtime.h>
#include <hip/hip_bf16.h>
#include <stdint.h>

#define T_TOK 8192
#define DIM   1024
#define FDIM  4096
#define NEXP  8
#define TKROWS (T_TOK * 2)   // total routed rows (top-2)

typedef float f32x4 __attribute__((ext_vector_type(4)));
typedef short s16x8 __attribute__((ext_vector_type(8)));

#define GLDS16(g, l) __builtin_amdgcn_global_load_lds(                         \
    (const __attribute__((address_space(1))) void*)(g),                        \
    (__attribute__((address_space(3))) void*)(l), 16, 0, 0)

static __device__ __forceinline__ unsigned short f2bf(float f) {
    unsigned int u = __float_as_uint(f);
    unsigned int r = u + 0x7FFFu + ((u >> 16) & 1u);
    return (unsigned short)(r >> 16);
}
static __device__ __forceinline__ float bf2f(unsigned short s) {
    return __uint_as_float((unsigned int)s << 16);
}

// ---- x f32 -> bf16 ----------------------------------------------------------
__global__ __launch_bounds__(256) void k_convert_x(const float4* __restrict__ x,
                                                   uint4* __restrict__ xb) {
    int i = blockIdx.x * 256 + threadIdx.x;      // each thread: 8 floats
    float4 a = x[2 * i], b = x[2 * i + 1];
    uint4 o;
    o.x = f2bf(a.x) | ((unsigned)f2bf(a.y) << 16);
    o.y = f2bf(a.z) | ((unsigned)f2bf(a.w) << 16);
    o.z = f2bf(b.x) | ((unsigned)f2bf(b.y) << 16);
    o.w = f2bf(b.z) | ((unsigned)f2bf(b.w) << 16);
    xb[i] = o;
}

// ---- weight transpose+convert: w [E][K][N] f32 -> wt [E][N][K] bf16 ---------
__global__ __launch_bounds__(256) void k_transpose(const float* __restrict__ w,
                                                   ushort* __restrict__ wt,
                                                   int K, int N) {
    int nt = N >> 6, ktl = K >> 6;
    int bid = blockIdx.x;
    int e = bid / (ktl * nt);
    int r = bid % (ktl * nt);
    int kb = r / nt, nb = r % nt;
    __shared__ ushort tile[64][65];
    const float* we = w + (size_t)e * K * N + (size_t)(kb * 64) * N + nb * 64;
    int t = threadIdx.x;
#pragma unroll
    for (int g = 0; g < 4; ++g) {
        int idx = t + g * 256;
        int row = idx >> 4, c4 = idx & 15;
        float4 v = *(const float4*)(we + (size_t)row * N + c4 * 4);
        tile[row][c4 * 4 + 0] = f2bf(v.x);
        tile[row][c4 * 4 + 1] = f2bf(v.y);
        tile[row][c4 * 4 + 2] = f2bf(v.z);
        tile[row][c4 * 4 + 3] = f2bf(v.w);
    }
    __syncthreads();
    ushort* wte = wt + (size_t)e * K * N + (size_t)(nb * 64) * K + kb * 64;
#pragma unroll
    for (int g = 0; g < 4; ++g) {
        int idx = t + g * 256;
        int n = idx >> 4, k4 = idx & 15;
        ushort4 o4;
        o4.x = tile[k4 * 4 + 0][n];
        o4.y = tile[k4 * 4 + 1][n];
        o4.z = tile[k4 * 4 + 2][n];
        o4.w = tile[k4 * 4 + 3][n];
        *(ushort4*)(wte + (size_t)n * K + k4 * 4) = o4;
    }
}

// ---- router: softmax(x @ gate_w + gate_b), top-2 ----------------------------
__global__ __launch_bounds__(256) void k_router(const float* __restrict__ x,
                                                const float* __restrict__ gw,
                                                const float* __restrict__ gb,
                                                int* __restrict__ idx_arr,
                                                float* __restrict__ w_arr,
                                                int* __restrict__ cnt) {
    int lane = threadIdx.x & 63, w = threadIdx.x >> 6;
    int tok = blockIdx.x * 4 + w;
    const float* xr = x + (size_t)tok * DIM;
    float acc[8];
#pragma unroll
    for (int e = 0; e < 8; ++e) acc[e] = 0.f;
    for (int it = 0; it < DIM / 64; ++it) {
        int d = it * 64 + lane;
        float xv = xr[d];
        const float4* g = (const float4*)(gw + (size_t)d * 8);
        float4 g0 = g[0], g1 = g[1];
        acc[0] += xv * g0.x; acc[1] += xv * g0.y;
        acc[2] += xv * g0.z; acc[3] += xv * g0.w;
        acc[4] += xv * g1.x; acc[5] += xv * g1.y;
        acc[6] += xv * g1.z; acc[7] += xv * g1.w;
    }
#pragma unroll
    for (int off = 32; off; off >>= 1)
#pragma unroll
        for (int e = 0; e < 8; ++e) acc[e] += __shfl_xor(acc[e], off);
    if (lane == 0) {
        float l[8], m = -1e30f;
#pragma unroll
        for (int e = 0; e < 8; ++e) { l[e] = acc[e] + gb[e]; m = fmaxf(m, l[e]); }
        float s = 0.f, p[8];
#pragma unroll
        for (int e = 0; e < 8; ++e) { p[e] = expf(l[e] - m); s += p[e]; }
        float inv = 1.f / s;
#pragma unroll
        for (int e = 0; e < 8; ++e) p[e] *= inv;
        int i0 = 0;
#pragma unroll
        for (int e = 1; e < 8; ++e) if (p[e] > p[i0]) i0 = e;
        int i1 = (i0 == 0) ? 1 : 0;
#pragma unroll
        for (int e = 0; e < 8; ++e) if (e != i0 && p[e] > p[i1]) i1 = e;
        idx_arr[tok * 2 + 0] = i0;  w_arr[tok * 2 + 0] = p[i0];
        idx_arr[tok * 2 + 1] = i1;  w_arr[tok * 2 + 1] = p[i1];
        atomicAdd(&cnt[i0], 1);
        atomicAdd(&cnt[i1], 1);
    }
}

__global__ void k_scan(const int* __restrict__ cnt, int* __restrict__ offs) {
    if (threadIdx.x == 0) {
        int s = 0;
        for (int e = 0; e < NEXP; ++e) { offs[e] = s; s += cnt[e]; }
        offs[NEXP] = s;
    }
}

__global__ __launch_bounds__(256) void k_fill(const int* __restrict__ idx_arr,
                                              const float* __restrict__ w_arr,
                                              const int* __restrict__ offs,
                                              int* __restrict__ fill,
                                              int* __restrict__ row_token,
                                              int* __restrict__ tok_row) {
    int t = blockIdx.x * 256 + threadIdx.x;
    if (t >= T_TOK) return;
#pragma unroll
    for (int k = 0; k < 2; ++k) {
        int e = idx_arr[t * 2 + k];
        int slot = atomicAdd(&fill[e], 1);
        int r = offs[e] + slot;
        row_token[r] = t;
        tok_row[t * 2 + k] = r;
    }
}

// ========== depth-2 prefetch (3 LDS buffers) counted-vmcnt grouped GEMMs =====
// Tile BM=128 x BN=256, BK=64; 512 thr = 8 waves (2M x 4N); per-wave 64x64
// (acc[4][4]). 6 global_load_lds per thread per K-tile (2 A + 4 B).
// Schedule: STAGE(t+2) -> vmcnt(12) [drains tile t, leaves 12 in flight]
// -> barrier -> COMPUTE(t) -> barrier. Load->use window = 2 iterations.
// T2 source-swizzle (verified 0 conflicts): physical 16B slot s at LDS row r
// holds logical slot s ^ (r&7), achieved by per-lane GLOBAL offset ksw;
// ds_reads XOR the slot with (row&7) == (lane&7).

#define STAGEG(buf, kt)                                                        \
    do {                                                                       \
        _Pragma("unroll")                                                      \
        for (int g = 0; g < 2; ++g) GLDS16(asrc[g] + (kt) * 64, &As[buf][acoff[g]]); \
        _Pragma("unroll")                                                      \
        for (int g = 0; g < 4; ++g) GLDS16(bsrc[g] + (kt) * 64, &Bs[buf][bcoff[g]]); \
    } while (0)

#define COMPUTEG(buf)                                                          \
    do {                                                                       \
        _Pragma("unroll")                                                      \
        for (int ks = 0; ks < 2; ++ks) {                                       \
            int sx = (((ks * 4 + (lane >> 4)) ^ (lane & 7)) << 3);             \
            s16x8 a[4], b[4];                                                  \
            _Pragma("unroll")                                                  \
            for (int m = 0; m < 4; ++m)                                        \
                a[m] = *(const s16x8*)&As[buf][(wm * 64 + m * 16 + (lane & 15)) * 64 + sx]; \
            _Pragma("unroll")                                                  \
            for (int n = 0; n < 4; ++n)                                        \
                b[n] = *(const s16x8*)&Bs[buf][(wn * 64 + n * 16 + (lane & 15)) * 64 + sx]; \
            _Pragma("unroll")                                                  \
            for (int m = 0; m < 4; ++m)                                        \
                _Pragma("unroll")                                              \
                for (int n = 0; n < 4; ++n)                                    \
                    acc[m][n] = __builtin_amdgcn_mfma_f32_16x16x32_bf16(a[m], b[n], acc[m][n], 0, 0, 0); \
        }                                                                      \
    } while (0)

#define KLOOP(NT)                                                              \
    do {                                                                       \
        STAGEG(0, 0);                                                          \
        STAGEG(1, 1);                                                          \
        int cb = 0;                                                            \
        for (int kt = 0; kt < (NT) - 2; ++kt) {                                \
            int sb = cb + 2; sb = sb >= 3 ? sb - 3 : sb;                       \
            STAGEG(sb, kt + 2);                                                \
            asm volatile("s_waitcnt vmcnt(12)" ::: "memory");                  \
            __builtin_amdgcn_sched_barrier(0);                                 \
            __builtin_amdgcn_s_barrier();                                      \
            COMPUTEG(cb);                                                      \
            __builtin_amdgcn_s_barrier();                                      \
            cb = cb + 1 >= 3 ? 0 : cb + 1;                                     \
        }                                                                      \
        asm volatile("s_waitcnt vmcnt(6)" ::: "memory");                       \
        __builtin_amdgcn_sched_barrier(0);                                     \
        __builtin_amdgcn_s_barrier();                                          \
        COMPUTEG(cb);                                                          \
        __builtin_amdgcn_s_barrier();                                          \
        cb = cb + 1 >= 3 ? 0 : cb + 1;                                         \
        asm volatile("s_waitcnt vmcnt(0)" ::: "memory");                       \
        __builtin_amdgcn_sched_barrier(0);                                     \
        __builtin_amdgcn_s_barrier();                                          \
        COMPUTEG(cb);                                                          \
    } while (0)

// ---- GEMM1: h = silu(x_gathered @ w1t[e]^T + b1[e])  [M=ne, N=4096, K=1024] -
__global__ __launch_bounds__(512) void k_gemm1(const ushort* __restrict__ xb,
                                               const ushort* __restrict__ w1t,
                                               const float* __restrict__ b1,
                                               const int* __restrict__ cnt,
                                               const int* __restrict__ offs,
                                               const int* __restrict__ row_token,
                                               ushort* __restrict__ h) {
    int bid = blockIdx.x;                 // e * (16*128) + ct * 128 + rt
    int e  = bid >> 11;
    int ct = (bid >> 7) & 15;
    int rt = bid & 127;
    int ne = cnt[e];
    if (rt * 128 >= ne) return;
    int base = offs[e];

    __shared__ __align__(16) ushort As[3][128 * 64];   // 48 KB
    __shared__ __align__(16) ushort Bs[3][256 * 64];   // 96 KB

    int tid = threadIdx.x, lane = tid & 63, wid = tid >> 6;
    int wm = wid >> 2, wn = wid & 3;
    int ksw = ((lane & 7) ^ ((lane >> 3) & 7)) * 8;

    const ushort* asrc[2];
    const ushort* bsrc[4];
    int acoff[2], bcoff[4];
    const ushort* w1e = w1t + (size_t)e * FDIM * DIM;
#pragma unroll
    for (int g = 0; g < 2; ++g) {
        int row = wid * 16 + g * 8 + (lane >> 3);
        int grow = base + rt * 128 + row;
        grow = grow < TKROWS ? grow : TKROWS - 1;
        asrc[g] = xb + (size_t)row_token[grow] * DIM + ksw;
        acoff[g] = wid * 1024 + g * 512;
    }
#pragma unroll
    for (int g = 0; g < 4; ++g) {
        int row = wid * 32 + g * 8 + (lane >> 3);
        bsrc[g] = w1e + (size_t)(ct * 256 + row) * DIM + ksw;
        bcoff[g] = wid * 2048 + g * 512;
    }

    f32x4 acc[4][4] = {};
    KLOOP(DIM / 64);

    const float* b1e = b1 + e * FDIM + ct * 256;
#pragma unroll
    for (int m = 0; m < 4; ++m) {
#pragma unroll
        for (int r = 0; r < 4; ++r) {
            int rloc = wm * 64 + m * 16 + ((lane >> 4) << 2) + r;
            int rexp = rt * 128 + rloc;
            if (rexp >= ne) continue;
            ushort* hrow = h + (size_t)(base + rexp) * FDIM + ct * 256;
#pragma unroll
            for (int n = 0; n < 4; ++n) {
                int col = wn * 64 + n * 16 + (lane & 15);
                float v = acc[m][n][r] + b1e[col];
                float si = v / (1.f + __expf(-v));
                hrow[col] = f2bf(si);
            }
        }
    }
}

// ---- GEMM2: y[row] = h[row] @ w2t[e]^T + b2[e]   [M=ne, N=1024, K=4096] -----
__global__ __launch_bounds__(512) void k_gemm2(const ushort* __restrict__ h,
                                               const ushort* __restrict__ w2t,
                                               const float* __restrict__ b2,
                                               const int* __restrict__ cnt,
                                               const int* __restrict__ offs,
                                               ushort* __restrict__ y) {
    int bid = blockIdx.x;                 // e * (4*128) + ct * 128 + rt
    int e  = bid >> 9;
    int ct = (bid >> 7) & 3;
    int rt = bid & 127;
    int ne = cnt[e];
    if (rt * 128 >= ne) return;
    int base = offs[e];

    __shared__ __align__(16) ushort As[3][128 * 64];   // 48 KB
    __shared__ __align__(16) ushort Bs[3][256 * 64];   // 96 KB

    int tid = threadIdx.x, lane = tid & 63, wid = tid >> 6;
    int wm = wid >> 2, wn = wid & 3;
    int ksw = ((lane & 7) ^ ((lane >> 3) & 7)) * 8;

    const ushort* asrc[2];
    const ushort* bsrc[4];
    int acoff[2], bcoff[4];
    const ushort* w2e = w2t + (size_t)e * DIM * FDIM;
#pragma unroll
    for (int g = 0; g < 2; ++g) {
        int row = wid * 16 + g * 8 + (lane >> 3);
        int grow = base + rt * 128 + row;
        grow = grow < TKROWS ? grow : TKROWS - 1;
        asrc[g] = h + (size_t)grow * FDIM + ksw;
        acoff[g] = wid * 1024 + g * 512;
    }
#pragma unroll
    for (int g = 0; g < 4; ++g) {
        int row = wid * 32 + g * 8 + (lane >> 3);
        bsrc[g] = w2e + (size_t)(ct * 256 + row) * FDIM + ksw;
        bcoff[g] = wid * 2048 + g * 512;
    }

    f32x4 acc[4][4] = {};
    KLOOP(FDIM / 64);

    const float* b2e = b2 + e * DIM + ct * 256;
#pragma unroll
    for (int m = 0; m < 4; ++m) {
#pragma unroll
        for (int r = 0; r < 4; ++r) {
            int rloc = wm * 64 + m * 16 + ((lane >> 4) << 2) + r;
            int rexp = rt * 128 + rloc;
            if (rexp >= ne) continue;
            ushort* yrow = y + (size_t)(base + rexp) * DIM + ct * 256;
#pragma unroll
            for (int n = 0; n < 4; ++n) {
                int col = wn * 64 + n * 16 + (lane & 15);
                yrow[col] = f2bf(acc[m][n][r] + b2e[col]);
            }
        }
    }
}

// ---- combine: out[t] = w0*y[r0] + w1*y[r1] ----------------------------------
__global__ __launch_bounds__(256) void k_combine(const ushort* __restrict__ y,
                                                 const int* __restrict__ tok_row,
                                                 const float* __restrict__ w_arr,
                                                 float* __restrict__ out) {
    int gid = blockIdx.x * 256 + threadIdx.x;   // T_TOK*DIM/8 threads
    int t = gid >> 7;                            // 128 8-elem chunks per token
    int c = gid & 127;
    int r0 = tok_row[t * 2], r1 = tok_row[t * 2 + 1];
    float w0 = w_arr[t * 2], w1 = w_arr[t * 2 + 1];
    uint4 a = *(const uint4*)(y + (size_t)r0 * DIM + c * 8);
    uint4 b = *(const uint4*)(y + (size_t)r1 * DIM + c * 8);
    float4 o0, o1;
    o0.x = w0 * bf2f(a.x & 0xFFFF) + w1 * bf2f(b.x & 0xFFFF);
    o0.y = w0 * bf2f(a.x >> 16)    + w1 * bf2f(b.x >> 16);
    o0.z = w0 * bf2f(a.y & 0xFFFF) + w1 * bf2f(b.y & 0xFFFF);
    o0.w = w0 * bf2f(a.y >> 16)    + w1 * bf2f(b.y >> 16);
    o1.x = w0 * bf2f(a.z & 0xFFFF) + w1 * bf2f(b.z & 0xFFFF);
    o1.y = w0 * bf2f(a.z >> 16)    + w1 * bf2f(b.z >> 16);
    o1.z = w0 * bf2f(a.w & 0xFFFF) + w1 * bf2f(b.w & 0xFFFF);
    o1.w = w0 * bf2f(a.w >> 16)    + w1 * bf2f(b.w >> 16);
    float4* op = (float4*)(out + (size_t)t * DIM + c * 8);
    op[0] = o0;
    op[1] = o1;
}

extern "C" void kernel_launch(void* const* d_in, const int* in_sizes, int n_in,
                              void* d_out, int out_size, void* d_ws, size_t ws_size,
                              hipStream_t stream) {
    const float* x      = (const float*)d_in[0];
    const float* gate_w = (const float*)d_in[1];
    const float* gate_b = (const float*)d_in[2];
    const float* w1     = (const float*)d_in[3];
    const float* b1     = (const float*)d_in[4];
    const float* w2     = (const float*)d_in[5];
    const float* b2     = (const float*)d_in[6];
    float* out = (float*)d_out;

    char* ws = (char*)d_ws;
    size_t o = 0;
    ushort* h  = (ushort*)(ws + o); o += (size_t)TKROWS * FDIM * 2;      // 134 MB
    ushort* wt = (ushort*)(ws + o); o += (size_t)NEXP * DIM * FDIM * 2;  // 67 MB (w1t then w2t)
    ushort* y  = (ushort*)(ws + o);                                      // 33.5 MB
    ushort* xb = y;                 o += (size_t)TKROWS * DIM * 2;       // xb (16.8MB) dies before y is written
    int*   idx_arr   = (int*)(ws + o);   o += TKROWS * 4;
    float* w_arr     = (float*)(ws + o); o += TKROWS * 4;
    int*   row_token = (int*)(ws + o);   o += TKROWS * 4;
    int*   tok_row   = (int*)(ws + o);   o += TKROWS * 4;
    int*   cnt  = (int*)(ws + o);       // 8 ints
    int*   offs = cnt + 8;              // 9 ints
    int*   fill = cnt + 24;             // 8 ints

    hipMemsetAsync(cnt, 0, 256, stream);

    k_convert_x<<<4096, 256, 0, stream>>>((const float4*)x, (uint4*)xb);
    k_router<<<T_TOK / 4, 256, 0, stream>>>(x, gate_w, gate_b, idx_arr, w_arr, cnt);
    k_scan<<<1, 64, 0, stream>>>(cnt, offs);
    k_fill<<<T_TOK / 256, 256, 0, stream>>>(idx_arr, w_arr, offs, fill, row_token, tok_row);

    k_transpose<<<NEXP * (DIM / 64) * (FDIM / 64), 256, 0, stream>>>(w1, wt, DIM, FDIM);
    k_gemm1<<<NEXP * 16 * 128, 512, 0, stream>>>(xb, wt, b1, cnt, offs, row_token, h);
    k_transpose<<<NEXP * (FDIM / 64) * (DIM / 64), 256, 0, stream>>>(w2, wt, FDIM, DIM);
    k_gemm2<<<NEXP * 4 * 128, 512, 0, stream>>>(h, wt, b2, cnt, offs, y);
    k_combine<<<T_TOK * DIM / 8 / 256, 256, 0, stream>>>(y, tok_row, w_arr, out);
}

// Round 8
// 883.205 us; speedup vs baseline: 1.2772x; 1.2772x over previous
//
#include <hip/hip_runtime.h>
#include <hip/hip_bf16.h>
#include <stdint.h>

#define T_TOK 8192
#define DIM   1024
#define FDIM  4096
#define NEXP  8
#define TKROWS (T_TOK * 2)   // total routed rows (top-2)

typedef float f32x4 __attribute__((ext_vector_type(4)));
typedef short s16x8 __attribute__((ext_vector_type(8)));

#define GLDS16(g, l) __builtin_amdgcn_global_load_lds(                         \
    (const __attribute__((address_space(1))) void*)(g),                        \
    (__attribute__((address_space(3))) void*)(l), 16, 0, 0)

static __device__ __forceinline__ unsigned short f2bf(float f) {
    unsigned int u = __float_as_uint(f);
    unsigned int r = u + 0x7FFFu + ((u >> 16) & 1u);
    return (unsigned short)(r >> 16);
}
static __device__ __forceinline__ float bf2f(unsigned short s) {
    return __uint_as_float((unsigned int)s << 16);
}

// ---- x f32 -> bf16 ----------------------------------------------------------
__global__ __launch_bounds__(256) void k_convert_x(const float4* __restrict__ x,
                                                   uint4* __restrict__ xb) {
    int i = blockIdx.x * 256 + threadIdx.x;
    float4 a = x[2 * i], b = x[2 * i + 1];
    uint4 o;
    o.x = f2bf(a.x) | ((unsigned)f2bf(a.y) << 16);
    o.y = f2bf(a.z) | ((unsigned)f2bf(a.w) << 16);
    o.z = f2bf(b.x) | ((unsigned)f2bf(b.y) << 16);
    o.w = f2bf(b.z) | ((unsigned)f2bf(b.w) << 16);
    xb[i] = o;
}

// ---- weight transpose+convert: w [E][K][N] f32 -> wt [E][N][K] bf16 ---------
__global__ __launch_bounds__(256) void k_transpose(const float* __restrict__ w,
                                                   ushort* __restrict__ wt,
                                                   int K, int N) {
    int nt = N >> 6, ktl = K >> 6;
    int bid = blockIdx.x;
    int e = bid / (ktl * nt);
    int r = bid % (ktl * nt);
    int kb = r / nt, nb = r % nt;
    __shared__ ushort tile[64][65];
    const float* we = w + (size_t)e * K * N + (size_t)(kb * 64) * N + nb * 64;
    int t = threadIdx.x;
#pragma unroll
    for (int g = 0; g < 4; ++g) {
        int idx = t + g * 256;
        int row = idx >> 4, c4 = idx & 15;
        float4 v = *(const float4*)(we + (size_t)row * N + c4 * 4);
        tile[row][c4 * 4 + 0] = f2bf(v.x);
        tile[row][c4 * 4 + 1] = f2bf(v.y);
        tile[row][c4 * 4 + 2] = f2bf(v.z);
        tile[row][c4 * 4 + 3] = f2bf(v.w);
    }
    __syncthreads();
    ushort* wte = wt + (size_t)e * K * N + (size_t)(nb * 64) * K + kb * 64;
#pragma unroll
    for (int g = 0; g < 4; ++g) {
        int idx = t + g * 256;
        int n = idx >> 4, k4 = idx & 15;
        ushort4 o4;
        o4.x = tile[k4 * 4 + 0][n];
        o4.y = tile[k4 * 4 + 1][n];
        o4.z = tile[k4 * 4 + 2][n];
        o4.w = tile[k4 * 4 + 3][n];
        *(ushort4*)(wte + (size_t)n * K + k4 * 4) = o4;
    }
}

// ---- router: softmax(x @ gate_w + gate_b), top-2 ----------------------------
__global__ __launch_bounds__(256) void k_router(const float* __restrict__ x,
                                                const float* __restrict__ gw,
                                                const float* __restrict__ gb,
                                                int* __restrict__ idx_arr,
                                                float* __restrict__ w_arr,
                                                int* __restrict__ cnt) {
    int lane = threadIdx.x & 63, w = threadIdx.x >> 6;
    int tok = blockIdx.x * 4 + w;
    const float* xr = x + (size_t)tok * DIM;
    float acc[8];
#pragma unroll
    for (int e = 0; e < 8; ++e) acc[e] = 0.f;
    for (int it = 0; it < DIM / 64; ++it) {
        int d = it * 64 + lane;
        float xv = xr[d];
        const float4* g = (const float4*)(gw + (size_t)d * 8);
        float4 g0 = g[0], g1 = g[1];
        acc[0] += xv * g0.x; acc[1] += xv * g0.y;
        acc[2] += xv * g0.z; acc[3] += xv * g0.w;
        acc[4] += xv * g1.x; acc[5] += xv * g1.y;
        acc[6] += xv * g1.z; acc[7] += xv * g1.w;
    }
#pragma unroll
    for (int off = 32; off; off >>= 1)
#pragma unroll
        for (int e = 0; e < 8; ++e) acc[e] += __shfl_xor(acc[e], off);
    if (lane == 0) {
        float l[8], m = -1e30f;
#pragma unroll
        for (int e = 0; e < 8; ++e) { l[e] = acc[e] + gb[e]; m = fmaxf(m, l[e]); }
        float s = 0.f, p[8];
#pragma unroll
        for (int e = 0; e < 8; ++e) { p[e] = expf(l[e] - m); s += p[e]; }
        float inv = 1.f / s;
#pragma unroll
        for (int e = 0; e < 8; ++e) p[e] *= inv;
        int i0 = 0;
#pragma unroll
        for (int e = 1; e < 8; ++e) if (p[e] > p[i0]) i0 = e;
        int i1 = (i0 == 0) ? 1 : 0;
#pragma unroll
        for (int e = 0; e < 8; ++e) if (e != i0 && p[e] > p[i1]) i1 = e;
        idx_arr[tok * 2 + 0] = i0;  w_arr[tok * 2 + 0] = p[i0];
        idx_arr[tok * 2 + 1] = i1;  w_arr[tok * 2 + 1] = p[i1];
        atomicAdd(&cnt[i0], 1);
        atomicAdd(&cnt[i1], 1);
    }
}

__global__ void k_scan(const int* __restrict__ cnt, int* __restrict__ offs) {
    if (threadIdx.x == 0) {
        int s = 0;
        for (int e = 0; e < NEXP; ++e) { offs[e] = s; s += cnt[e]; }
        offs[NEXP] = s;
    }
}

__global__ __launch_bounds__(256) void k_fill(const int* __restrict__ idx_arr,
                                              const float* __restrict__ w_arr,
                                              const int* __restrict__ offs,
                                              int* __restrict__ fill,
                                              int* __restrict__ row_token,
                                              int* __restrict__ tok_row) {
    int t = blockIdx.x * 256 + threadIdx.x;
    if (t >= T_TOK) return;
#pragma unroll
    for (int k = 0; k < 2; ++k) {
        int e = idx_arr[t * 2 + k];
        int slot = atomicAdd(&fill[e], 1);
        int r = offs[e] + slot;
        row_token[r] = t;
        tok_row[t * 2 + k] = r;
    }
}

// ================= 256x256 8-phase grouped GEMM (T3+T4+T5) ===================
// LDS: As/Bs[2 buf][2 k-halves][256 rows][32 cols] ushort = 128 KB total.
// 512 thr = 8 waves (2M x 4N); per-wave C = 128x64 (acc[8][4]); BK=64.
// Per K-tile: 4 phases {ds_read quad ; 2 GLDS (one operand k-half) ; barrier;
// lgkmcnt(0); setprio(1); 16 MFMA; setprio(0); [vmcnt(8) ph2/ph4]; barrier}.
// Stage schedule (ledger, per-thread loads 2/phase):
//   ph1: A(t+1).h1 -> buf^1   ph2: B(t+1).h1 -> buf^1
//   ph3: A(t+2).h0 -> buf     ph4: B(t+2).h0 -> buf
// vmcnt(8) at ph2 drains t.h1 (needed ph3); at ph4 drains (t+1).h0 (needed
// next ph1). 8 loads always in flight; never drains to 0 in the loop.
// Tail: clamped tile indexes re-write identical data / dead regions (safe).
// Swizzle (both-sides involution, m173/#21): phys 16B slot p at row r holds
// logical k-group p ^ (r&3); staged via per-lane GLOBAL offset skg; read via
// swz. Residual read conflict ~4-way (32-col halves cap the spread).

#define MQ(MB, X0, X1, X2, X3)                                                 \
    acc[MB+0][0] = __builtin_amdgcn_mfma_f32_16x16x32_bf16(X0, b0, acc[MB+0][0], 0, 0, 0); \
    acc[MB+0][1] = __builtin_amdgcn_mfma_f32_16x16x32_bf16(X0, b1, acc[MB+0][1], 0, 0, 0); \
    acc[MB+0][2] = __builtin_amdgcn_mfma_f32_16x16x32_bf16(X0, b2, acc[MB+0][2], 0, 0, 0); \
    acc[MB+0][3] = __builtin_amdgcn_mfma_f32_16x16x32_bf16(X0, b3, acc[MB+0][3], 0, 0, 0); \
    acc[MB+1][0] = __builtin_amdgcn_mfma_f32_16x16x32_bf16(X1, b0, acc[MB+1][0], 0, 0, 0); \
    acc[MB+1][1] = __builtin_amdgcn_mfma_f32_16x16x32_bf16(X1, b1, acc[MB+1][1], 0, 0, 0); \
    acc[MB+1][2] = __builtin_amdgcn_mfma_f32_16x16x32_bf16(X1, b2, acc[MB+1][2], 0, 0, 0); \
    acc[MB+1][3] = __builtin_amdgcn_mfma_f32_16x16x32_bf16(X1, b3, acc[MB+1][3], 0, 0, 0); \
    acc[MB+2][0] = __builtin_amdgcn_mfma_f32_16x16x32_bf16(X2, b0, acc[MB+2][0], 0, 0, 0); \
    acc[MB+2][1] = __builtin_amdgcn_mfma_f32_16x16x32_bf16(X2, b1, acc[MB+2][1], 0, 0, 0); \
    acc[MB+2][2] = __builtin_amdgcn_mfma_f32_16x16x32_bf16(X2, b2, acc[MB+2][2], 0, 0, 0); \
    acc[MB+2][3] = __builtin_amdgcn_mfma_f32_16x16x32_bf16(X2, b3, acc[MB+2][3], 0, 0, 0); \
    acc[MB+3][0] = __builtin_amdgcn_mfma_f32_16x16x32_bf16(X3, b0, acc[MB+3][0], 0, 0, 0); \
    acc[MB+3][1] = __builtin_amdgcn_mfma_f32_16x16x32_bf16(X3, b1, acc[MB+3][1], 0, 0, 0); \
    acc[MB+3][2] = __builtin_amdgcn_mfma_f32_16x16x32_bf16(X3, b2, acc[MB+3][2], 0, 0, 0); \
    acc[MB+3][3] = __builtin_amdgcn_mfma_f32_16x16x32_bf16(X3, b3, acc[MB+3][3], 0, 0, 0)

#define SA2(DB, H, KT) do {                                                    \
    GLDS16(a0p + (KT) * 64 + (H) * 32, &As[DB][H][wid * 512]);                 \
    GLDS16(a1p + (KT) * 64 + (H) * 32, &As[DB][H][(wid + 8) * 512]); } while (0)
#define SB2(DB, H, KT) do {                                                    \
    GLDS16(b0p + (KT) * 64 + (H) * 32, &Bs[DB][H][wid * 512]);                 \
    GLDS16(b1p + (KT) * 64 + (H) * 32, &Bs[DB][H][(wid + 8) * 512]); } while (0)

#define PHASES2(BUF, H, STG1, STG2)                                            \
  { const ushort* Ab = &As[BUF][H][0];                                         \
    const ushort* Bb = &Bs[BUF][H][0];                                         \
    s16x8 b0 = *(const s16x8*)&Bb[bbase + 0 * 512];                            \
    s16x8 b1 = *(const s16x8*)&Bb[bbase + 1 * 512];                            \
    s16x8 b2 = *(const s16x8*)&Bb[bbase + 2 * 512];                            \
    s16x8 b3 = *(const s16x8*)&Bb[bbase + 3 * 512];                            \
    s16x8 x0 = *(const s16x8*)&Ab[abase + 0 * 512];                            \
    s16x8 x1 = *(const s16x8*)&Ab[abase + 1 * 512];                            \
    s16x8 x2 = *(const s16x8*)&Ab[abase + 2 * 512];                            \
    s16x8 x3 = *(const s16x8*)&Ab[abase + 3 * 512];                            \
    STG1;                                                                      \
    __builtin_amdgcn_sched_barrier(0);                                         \
    __builtin_amdgcn_s_barrier();                                              \
    asm volatile("s_waitcnt lgkmcnt(0)" ::: "memory");                         \
    __builtin_amdgcn_sched_barrier(0);                                         \
    __builtin_amdgcn_s_setprio(1);                                             \
    MQ(0, x0, x1, x2, x3);                                                     \
    __builtin_amdgcn_s_setprio(0);                                             \
    __builtin_amdgcn_s_barrier();                                              \
    s16x8 x4 = *(const s16x8*)&Ab[abase + 4 * 512];                            \
    s16x8 x5 = *(const s16x8*)&Ab[abase + 5 * 512];                            \
    s16x8 x6 = *(const s16x8*)&Ab[abase + 6 * 512];                            \
    s16x8 x7 = *(const s16x8*)&Ab[abase + 7 * 512];                            \
    STG2;                                                                      \
    __builtin_amdgcn_sched_barrier(0);                                         \
    __builtin_amdgcn_s_barrier();                                              \
    asm volatile("s_waitcnt lgkmcnt(0)" ::: "memory");                         \
    __builtin_amdgcn_sched_barrier(0);                                         \
    __builtin_amdgcn_s_setprio(1);                                             \
    MQ(4, x4, x5, x6, x7);                                                     \
    __builtin_amdgcn_s_setprio(0);                                             \
    asm volatile("s_waitcnt vmcnt(8)" ::: "memory");                           \
    __builtin_amdgcn_sched_barrier(0);                                         \
    __builtin_amdgcn_s_barrier();                                              \
  }

#define KLOOP8(NT)                                                             \
  do {                                                                         \
    SA2(0, 0, 0); SB2(0, 0, 0);                                                \
    SA2(0, 1, 0); SB2(0, 1, 0);                                                \
    SA2(1, 0, 1); SB2(1, 0, 1);                                                \
    asm volatile("s_waitcnt vmcnt(8)" ::: "memory");                           \
    __builtin_amdgcn_sched_barrier(0);                                         \
    __builtin_amdgcn_s_barrier();                                              \
    for (int t = 0; t < (NT); ++t) {                                           \
      int buf = t & 1, sb = buf ^ 1;                                           \
      int t1 = t + 1 < (NT) ? t + 1 : (NT) - 1;                                \
      int t2 = t + 2 < (NT) ? t + 2 : (NT) - 1;                                \
      PHASES2(buf, 0, SA2(sb, 1, t1), SB2(sb, 1, t1));                         \
      PHASES2(buf, 1, SA2(buf, 0, t2), SB2(buf, 0, t2));                       \
    }                                                                          \
    asm volatile("s_waitcnt vmcnt(0)" ::: "memory");                           \
  } while (0)

// ---- GEMM1: h = silu(x_gathered @ w1t[e]^T + b1[e])  [M=ne, N=4096, K=1024] -
__global__ __launch_bounds__(512) void k_gemm1(const ushort* __restrict__ xb,
                                               const ushort* __restrict__ w1t,
                                               const float* __restrict__ b1,
                                               const int* __restrict__ cnt,
                                               const int* __restrict__ offs,
                                               const int* __restrict__ row_token,
                                               ushort* __restrict__ h) {
    int bid = blockIdx.x;                 // e*(32*16) + rt*16 + ct
    int e  = bid >> 9;
    int rt = (bid >> 4) & 31;
    int ct = bid & 15;
    int ne = cnt[e];
    if (rt * 256 >= ne) return;
    int base = offs[e];

    __shared__ __align__(16) ushort As[2][2][8192];
    __shared__ __align__(16) ushort Bs[2][2][8192];

    int tid = threadIdx.x, lane = tid & 63, wid = tid >> 6;
    int wm = wid >> 2, wn = wid & 3;
    int swz   = ((lane >> 4) ^ (lane & 3)) * 8;       // read slot swizzle
    int abase = (wm * 128 + (lane & 15)) * 32 + swz;
    int bbase = (wn * 64  + (lane & 15)) * 32 + swz;
    int skg   = ((lane & 3) ^ ((lane >> 2) & 3)) * 8; // staged source k-group

    int r0 = wid * 16 + (lane >> 2);
    int r1 = r0 + 128;
    int g0 = base + rt * 256 + r0; g0 = g0 < TKROWS ? g0 : TKROWS - 1;
    int g1 = base + rt * 256 + r1; g1 = g1 < TKROWS ? g1 : TKROWS - 1;
    const ushort* a0p = xb + (size_t)row_token[g0] * DIM + skg;
    const ushort* a1p = xb + (size_t)row_token[g1] * DIM + skg;
    const ushort* w1e = w1t + (size_t)e * FDIM * DIM;
    const ushort* b0p = w1e + (size_t)(ct * 256 + r0) * DIM + skg;
    const ushort* b1p = w1e + (size_t)(ct * 256 + r1) * DIM + skg;

    f32x4 acc[8][4] = {};
    KLOOP8(DIM / 64);

    const float* b1e = b1 + e * FDIM + ct * 256;
#pragma unroll
    for (int m = 0; m < 8; ++m) {
#pragma unroll
        for (int r = 0; r < 4; ++r) {
            int rloc = wm * 128 + m * 16 + ((lane >> 4) << 2) + r;
            int rexp = rt * 256 + rloc;
            if (rexp >= ne) continue;
            ushort* hrow = h + (size_t)(base + rexp) * FDIM + ct * 256;
#pragma unroll
            for (int n = 0; n < 4; ++n) {
                int col = wn * 64 + n * 16 + (lane & 15);
                float v = acc[m][n][r] + b1e[col];
                float si = v / (1.f + __expf(-v));
                hrow[col] = f2bf(si);
            }
        }
    }
}

// ---- GEMM2: y[row] = h[row] @ w2t[e]^T + b2[e]   [M=ne, N=1024, K=4096] -----
__global__ __launch_bounds__(512) void k_gemm2(const ushort* __restrict__ h,
                                               const ushort* __restrict__ w2t,
                                               const float* __restrict__ b2,
                                               const int* __restrict__ cnt,
                                               const int* __restrict__ offs,
                                               ushort* __restrict__ y) {
    int bid = blockIdx.x;                 // e*(32*4) + rt*4 + ct
    int e  = bid >> 7;
    int rt = (bid >> 2) & 31;
    int ct = bid & 3;
    int ne = cnt[e];
    if (rt * 256 >= ne) return;
    int base = offs[e];

    __shared__ __align__(16) ushort As[2][2][8192];
    __shared__ __align__(16) ushort Bs[2][2][8192];

    int tid = threadIdx.x, lane = tid & 63, wid = tid >> 6;
    int wm = wid >> 2, wn = wid & 3;
    int swz   = ((lane >> 4) ^ (lane & 3)) * 8;
    int abase = (wm * 128 + (lane & 15)) * 32 + swz;
    int bbase = (wn * 64  + (lane & 15)) * 32 + swz;
    int skg   = ((lane & 3) ^ ((lane >> 2) & 3)) * 8;

    int r0 = wid * 16 + (lane >> 2);
    int r1 = r0 + 128;
    int g0 = base + rt * 256 + r0; g0 = g0 < TKROWS ? g0 : TKROWS - 1;
    int g1 = base + rt * 256 + r1; g1 = g1 < TKROWS ? g1 : TKROWS - 1;
    const ushort* a0p = h + (size_t)g0 * FDIM + skg;
    const ushort* a1p = h + (size_t)g1 * FDIM + skg;
    const ushort* w2e = w2t + (size_t)e * DIM * FDIM;
    const ushort* b0p = w2e + (size_t)(ct * 256 + r0) * FDIM + skg;
    const ushort* b1p = w2e + (size_t)(ct * 256 + r1) * FDIM + skg;

    f32x4 acc[8][4] = {};
    KLOOP8(FDIM / 64);

    const float* b2e = b2 + e * DIM + ct * 256;
#pragma unroll
    for (int m = 0; m < 8; ++m) {
#pragma unroll
        for (int r = 0; r < 4; ++r) {
            int rloc = wm * 128 + m * 16 + ((lane >> 4) << 2) + r;
            int rexp = rt * 256 + rloc;
            if (rexp >= ne) continue;
            ushort* yrow = y + (size_t)(base + rexp) * DIM + ct * 256;
#pragma unroll
            for (int n = 0; n < 4; ++n) {
                int col = wn * 64 + n * 16 + (lane & 15);
                yrow[col] = f2bf(acc[m][n][r] + b2e[col]);
            }
        }
    }
}

// ---- combine: out[t] = w0*y[r0] + w1*y[r1] ----------------------------------
__global__ __launch_bounds__(256) void k_combine(const ushort* __restrict__ y,
                                                 const int* __restrict__ tok_row,
                                                 const float* __restrict__ w_arr,
                                                 float* __restrict__ out) {
    int gid = blockIdx.x * 256 + threadIdx.x;
    int t = gid >> 7;
    int c = gid & 127;
    int r0 = tok_row[t * 2], r1 = tok_row[t * 2 + 1];
    float w0 = w_arr[t * 2], w1 = w_arr[t * 2 + 1];
    uint4 a = *(const uint4*)(y + (size_t)r0 * DIM + c * 8);
    uint4 b = *(const uint4*)(y + (size_t)r1 * DIM + c * 8);
    float4 o0, o1;
    o0.x = w0 * bf2f(a.x & 0xFFFF) + w1 * bf2f(b.x & 0xFFFF);
    o0.y = w0 * bf2f(a.x >> 16)    + w1 * bf2f(b.x >> 16);
    o0.z = w0 * bf2f(a.y & 0xFFFF) + w1 * bf2f(b.y & 0xFFFF);
    o0.w = w0 * bf2f(a.y >> 16)    + w1 * bf2f(b.y >> 16);
    o1.x = w0 * bf2f(a.z & 0xFFFF) + w1 * bf2f(b.z & 0xFFFF);
    o1.y = w0 * bf2f(a.z >> 16)    + w1 * bf2f(b.z >> 16);
    o1.z = w0 * bf2f(a.w & 0xFFFF) + w1 * bf2f(b.w & 0xFFFF);
    o1.w = w0 * bf2f(a.w >> 16)    + w1 * bf2f(b.w >> 16);
    float4* op = (float4*)(out + (size_t)t * DIM + c * 8);
    op[0] = o0;
    op[1] = o1;
}

extern "C" void kernel_launch(void* const* d_in, const int* in_sizes, int n_in,
                              void* d_out, int out_size, void* d_ws, size_t ws_size,
                              hipStream_t stream) {
    const float* x      = (const float*)d_in[0];
    const float* gate_w = (const float*)d_in[1];
    const float* gate_b = (const float*)d_in[2];
    const float* w1     = (const float*)d_in[3];
    const float* b1     = (const float*)d_in[4];
    const float* w2     = (const float*)d_in[5];
    const float* b2     = (const float*)d_in[6];
    float* out = (float*)d_out;

    char* ws = (char*)d_ws;
    size_t o = 0;
    ushort* h  = (ushort*)(ws + o); o += (size_t)TKROWS * FDIM * 2;      // 134 MB
    ushort* wt = (ushort*)(ws + o); o += (size_t)NEXP * DIM * FDIM * 2;  // 67 MB (w1t then w2t)
    ushort* y  = (ushort*)(ws + o);                                      // 33.5 MB
    ushort* xb = y;                 o += (size_t)TKROWS * DIM * 2;       // xb dies before y written
    int*   idx_arr   = (int*)(ws + o);   o += TKROWS * 4;
    float* w_arr     = (float*)(ws + o); o += TKROWS * 4;
    int*   row_token = (int*)(ws + o);   o += TKROWS * 4;
    int*   tok_row   = (int*)(ws + o);   o += TKROWS * 4;
    int*   cnt  = (int*)(ws + o);       // 8 ints
    int*   offs = cnt + 8;              // 9 ints
    int*   fill = cnt + 24;             // 8 ints

    hipMemsetAsync(cnt, 0, 256, stream);

    k_convert_x<<<4096, 256, 0, stream>>>((const float4*)x, (uint4*)xb);
    k_router<<<T_TOK / 4, 256, 0, stream>>>(x, gate_w, gate_b, idx_arr, w_arr, cnt);
    k_scan<<<1, 64, 0, stream>>>(cnt, offs);
    k_fill<<<T_TOK / 256, 256, 0, stream>>>(idx_arr, w_arr, offs, fill, row_token, tok_row);

    k_transpose<<<NEXP * (DIM / 64) * (FDIM / 64), 256, 0, stream>>>(w1, wt, DIM, FDIM);
    k_gemm1<<<NEXP * 32 * 16, 512, 0, stream>>>(xb, wt, b1, cnt, offs, row_token, h);
    k_transpose<<<NEXP * (FDIM / 64) * (DIM / 64), 256, 0, stream>>>(w2, wt, FDIM, DIM);
    k_gemm2<<<NEXP * 32 * 4, 512, 0, stream>>>(h, wt, b2, cnt, offs, y);
    k_combine<<<T_TOK * DIM / 8 / 256, 256, 0, stream>>>(y, tok_row, w_arr, out);
}